// Round 1
// baseline (614.880 us; speedup 1.0000x reference)
//
#include <hip/hip_runtime.h>
#include <cstddef>
#include <cstdint>

#define POS_LEN    32768
#define NUM_NEG    64
#define N_RULES    262144
#define N_UNLABEL  131072
#define NUM_ENT    100000
#define NUM_REL    500
#define EMB_DIM    256
#define WEIGHT_DECAY 1e-5

__device__ __forceinline__ float softplusf_(float x) {
    // stable: max(x,0) + log1p(exp(-|x|))
    return fmaxf(x, 0.0f) + log1pf(expf(-fabsf(x)));
}
__device__ __forceinline__ float sigmoidf_(float x) {
    return 1.0f / (1.0f + expf(-x));
}
__device__ __forceinline__ float wave_sum(float v) {
#pragma unroll
    for (int m = 32; m >= 1; m >>= 1) v += __shfl_xor(v, m, 64);
    return v;  // all 64 lanes hold the sum
}

// One wave computes sum_d ent[h,d]*rel[r,d]*ent[t,d]; lane i covers dims [4i,4i+4)
__device__ __forceinline__ float triple_score(const float* __restrict__ ent,
                                              const float* __restrict__ rel,
                                              int h, int r, int t, int lane) {
    const float4 hv = *reinterpret_cast<const float4*>(ent + (size_t)h * EMB_DIM + lane * 4);
    const float4 rv = *reinterpret_cast<const float4*>(rel + (size_t)r * EMB_DIM + lane * 4);
    const float4 tv = *reinterpret_cast<const float4*>(ent + (size_t)t * EMB_DIM + lane * 4);
    float s = hv.x * rv.x * tv.x + hv.y * rv.y * tv.y +
              hv.z * rv.z * tv.z + hv.w * rv.w * tv.w;
    return wave_sum(s);
}

// ---- Kernel A: per-rule contrib -> atomic segment_sum into pi_grad ----
__global__ void rules_kernel(const float* __restrict__ conf,
                             const float* __restrict__ ent,
                             const float* __restrict__ rel,
                             const int* __restrict__ p1,
                             const int* __restrict__ p2,
                             const int* __restrict__ tnum,
                             const int* __restrict__ uids,
                             float* __restrict__ pi_grad) {
    const int lane = threadIdx.x & 63;
    const int rule = blockIdx.x * (blockDim.x >> 6) + (threadIdx.x >> 6);
    if (rule >= N_RULES) return;

    const int h1 = p1[rule * 3 + 0], r1 = p1[rule * 3 + 1], t1 = p1[rule * 3 + 2];
    float c = sigmoidf_(triple_score(ent, rel, h1, r1, t1, lane)) * conf[rule];
    if (tnum[rule] == 3) {  // wave-uniform branch
        const int h2 = p2[rule * 3 + 0], r2 = p2[rule * 3 + 1], t2 = p2[rule * 3 + 2];
        c *= sigmoidf_(triple_score(ent, rel, h2, r2, t2, lane));
    }
    if (lane == 0) atomicAdd(&pi_grad[uids[rule]], c);
}

// ---- Kernel B: unlabel loss (needs pi_grad) ----
__global__ void unlabel_kernel(const float* __restrict__ ent,
                               const float* __restrict__ rel,
                               const int* __restrict__ ut,
                               const float* __restrict__ pi_grad,
                               double* __restrict__ accum) {
    const int lane = threadIdx.x & 63;
    const int wid  = threadIdx.x >> 6;
    const int i    = blockIdx.x * (blockDim.x >> 6) + wid;
    float loss = 0.0f;
    if (i < N_UNLABEL) {
        const int h = ut[i * 3 + 0], r = ut[i * 3 + 1], t = ut[i * 3 + 2];
        const float su  = triple_score(ent, rel, h, r, t, lane);
        const float p   = sigmoidf_(su);
        const float tgt = fminf(fmaxf(p + pi_grad[i], 0.0f), 1.0f);
        loss = tgt * softplusf_(-su) + (1.0f - tgt) * softplusf_(su);
    }
    __shared__ float part[8];
    if (lane == 0) part[wid] = loss;
    __syncthreads();
    if (threadIdx.x == 0) {
        float b = 0.0f;
        for (int w = 0; w < (int)(blockDim.x >> 6); ++w) b += part[w];
        atomicAdd(&accum[2], (double)b);
    }
}

// ---- Kernel C: positive + negative softplus sums ----
__global__ void posneg_kernel(const float* __restrict__ pos,
                              const float* __restrict__ neg,
                              double* __restrict__ accum) {
    const int tid = blockIdx.x * blockDim.x + threadIdx.x;
    const int stride = gridDim.x * blockDim.x;
    float ps = 0.0f, ns = 0.0f;
    for (int i = tid; i < POS_LEN / 4; i += stride) {
        float4 v = reinterpret_cast<const float4*>(pos)[i];
        ps += softplusf_(-v.x) + softplusf_(-v.y) + softplusf_(-v.z) + softplusf_(-v.w);
    }
    for (int i = tid; i < (POS_LEN * NUM_NEG) / 4; i += stride) {
        float4 v = reinterpret_cast<const float4*>(neg)[i];
        ns += softplusf_(v.x) + softplusf_(v.y) + softplusf_(v.z) + softplusf_(v.w);
    }
    __shared__ float lp[8], ln[8];
    ps = wave_sum(ps); ns = wave_sum(ns);
    const int lane = threadIdx.x & 63, wid = threadIdx.x >> 6;
    if (lane == 0) { lp[wid] = ps; ln[wid] = ns; }
    __syncthreads();
    if (threadIdx.x == 0) {
        float bp = 0.0f, bn = 0.0f;
        for (int w = 0; w < (int)(blockDim.x >> 6); ++w) { bp += lp[w]; bn += ln[w]; }
        atomicAdd(&accum[0], (double)bp);
        atomicAdd(&accum[1], (double)bn);
    }
}

// ---- Kernel D: sum of squares (regularization) ----
__global__ void sq_kernel(const float* __restrict__ ent,
                          const float* __restrict__ rel,
                          double* __restrict__ accum) {
    const int tid = blockIdx.x * blockDim.x + threadIdx.x;
    const int stride = gridDim.x * blockDim.x;
    float s = 0.0f;
    const int n_ent4 = (NUM_ENT * EMB_DIM) / 4;    // 6,400,000
    const int n_rel4 = (NUM_REL * EMB_DIM) / 4;    // 32,000
    for (int i = tid; i < n_ent4; i += stride) {
        float4 v = reinterpret_cast<const float4*>(ent)[i];
        s += v.x * v.x + v.y * v.y + v.z * v.z + v.w * v.w;
    }
    for (int i = tid; i < n_rel4; i += stride) {
        float4 v = reinterpret_cast<const float4*>(rel)[i];
        s += v.x * v.x + v.y * v.y + v.z * v.z + v.w * v.w;
    }
    s = wave_sum(s);
    __shared__ float ls[8];
    const int lane = threadIdx.x & 63, wid = threadIdx.x >> 6;
    if (lane == 0) ls[wid] = s;
    __syncthreads();
    if (threadIdx.x == 0) {
        float b = 0.0f;
        for (int w = 0; w < (int)(blockDim.x >> 6); ++w) b += ls[w];
        atomicAdd(&accum[3], (double)b);
    }
}

// ---- Finalize ----
__global__ void finalize_kernel(const double* __restrict__ accum,
                                float* __restrict__ out) {
    double v = accum[0] / (double)POS_LEN
             + accum[1] / ((double)POS_LEN * (double)NUM_NEG)
             + accum[2] / (double)N_UNLABEL
             + WEIGHT_DECAY * accum[3];
    out[0] = (float)v;
}

extern "C" void kernel_launch(void* const* d_in, const int* in_sizes, int n_in,
                              void* d_out, int out_size, void* d_ws, size_t ws_size,
                              hipStream_t stream) {
    const float* pos  = (const float*)d_in[0];
    const float* neg  = (const float*)d_in[1];
    const float* conf = (const float*)d_in[2];
    const float* ent  = (const float*)d_in[3];
    const float* rel  = (const float*)d_in[4];
    const int*   p1   = (const int*)d_in[5];
    const int*   p2   = (const int*)d_in[6];
    const int*   tnum = (const int*)d_in[7];
    const int*   uids = (const int*)d_in[8];
    const int*   ut   = (const int*)d_in[9];

    float*  pi_grad = (float*)d_ws;
    double* accum   = (double*)((char*)d_ws + (size_t)N_UNLABEL * sizeof(float));

    // ws is poisoned 0xAA and never re-poisoned between replays: zero our region every call.
    hipMemsetAsync(d_ws, 0, (size_t)N_UNLABEL * sizeof(float) + 4 * sizeof(double), stream);

    // wave-per-rule: 256 threads = 4 waves/block
    rules_kernel<<<N_RULES / 4, 256, 0, stream>>>(conf, ent, rel, p1, p2, tnum, uids, pi_grad);
    unlabel_kernel<<<N_UNLABEL / 4, 256, 0, stream>>>(ent, rel, ut, pi_grad, accum);
    posneg_kernel<<<2048, 256, 0, stream>>>(pos, neg, accum);
    sq_kernel<<<2048, 256, 0, stream>>>(ent, rel, accum);
    finalize_kernel<<<1, 1, 0, stream>>>(accum, (float*)d_out);
}

// Round 2
// 260.737 us; speedup vs baseline: 2.3582x; 2.3582x over previous
//
#include <hip/hip_runtime.h>
#include <cstddef>
#include <cstdint>

#define POS_LEN    32768
#define NUM_NEG    64
#define N_RULES    262144
#define N_UNLABEL  131072
#define NUM_ENT    100000
#define NUM_REL    500
#define EMB_DIM    256
#define WEIGHT_DECAY 1e-5

__device__ __forceinline__ float softplusf_(float x) {
    return fmaxf(x, 0.0f) + log1pf(expf(-fabsf(x)));
}
__device__ __forceinline__ float sigmoidf_(float x) {
    return 1.0f / (1.0f + expf(-x));
}
// Sum within each 32-lane half of the wave (masks 1..16 stay inside the half).
__device__ __forceinline__ float half_sum32(float v) {
#pragma unroll
    for (int m = 1; m <= 16; m <<= 1) v += __shfl_xor(v, m, 64);
    return v;
}
__device__ __forceinline__ float wave_sum64(float v) {
#pragma unroll
    for (int m = 32; m >= 1; m >>= 1) v += __shfl_xor(v, m, 64);
    return v;
}

// Half-wave triple score: 32 lanes x float8 = 256 dims. l = lane & 31.
// After half_sum32, every lane of the half holds the full dot product.
__device__ __forceinline__ float triple_score_half(const float* __restrict__ ent,
                                                   const float* __restrict__ rel,
                                                   int h, int r, int t, int l) {
    const float4* hp = reinterpret_cast<const float4*>(ent + (size_t)h * EMB_DIM) + l * 2;
    const float4* rp = reinterpret_cast<const float4*>(rel + (size_t)r * EMB_DIM) + l * 2;
    const float4* tp = reinterpret_cast<const float4*>(ent + (size_t)t * EMB_DIM) + l * 2;
    float4 h0 = hp[0], h1 = hp[1];
    float4 r0 = rp[0], r1 = rp[1];
    float4 t0 = tp[0], t1 = tp[1];
    float s = h0.x * r0.x * t0.x + h0.y * r0.y * t0.y + h0.z * r0.z * t0.z + h0.w * r0.w * t0.w
            + h1.x * r1.x * t1.x + h1.y * r1.y * t1.y + h1.z * r1.z * t1.z + h1.w * r1.w * t1.w;
    return half_sum32(s);
}

// ---- Kernel A: per-rule contrib -> atomic segment_sum into pi_grad ----
// 2 rules per wave (one per 32-lane half), grid-stride.
__global__ void rules_kernel(const float* __restrict__ conf,
                             const float* __restrict__ ent,
                             const float* __restrict__ rel,
                             const int* __restrict__ p1,
                             const int* __restrict__ p2,
                             const int* __restrict__ tnum,
                             const int* __restrict__ uids,
                             float* __restrict__ pi_grad) {
    const int lane = threadIdx.x & 63;
    const int l    = lane & 31;
    const int half = lane >> 5;
    const int wave  = blockIdx.x * (blockDim.x >> 6) + (threadIdx.x >> 6);
    const int nwave = gridDim.x * (blockDim.x >> 6);
    const int npair = N_RULES / 2;

    for (int pi = wave; pi < npair; pi += nwave) {
        const int rule = pi * 2 + half;
        const int h1 = p1[rule * 3 + 0], r1 = p1[rule * 3 + 1], t1 = p1[rule * 3 + 2];
        float c = sigmoidf_(triple_score_half(ent, rel, h1, r1, t1, l)) * conf[rule];
        if (tnum[rule] == 3) {  // uniform within the 32-lane half
            const int h2 = p2[rule * 3 + 0], r2 = p2[rule * 3 + 1], t2 = p2[rule * 3 + 2];
            c *= sigmoidf_(triple_score_half(ent, rel, h2, r2, t2, l));
        }
        if (l == 0) atomicAdd(&pi_grad[uids[rule]], c);
    }
}

// ---- Kernel B: unlabel loss (needs pi_grad). 2 triples per wave, grid-stride,
// one f64 atomic per BLOCK (not per 4 triples). ----
__global__ void unlabel_kernel(const float* __restrict__ ent,
                               const float* __restrict__ rel,
                               const int* __restrict__ ut,
                               const float* __restrict__ pi_grad,
                               double* __restrict__ accum) {
    const int lane = threadIdx.x & 63;
    const int l    = lane & 31;
    const int half = lane >> 5;
    const int wid  = threadIdx.x >> 6;
    const int wave  = blockIdx.x * (blockDim.x >> 6) + wid;
    const int nwave = gridDim.x * (blockDim.x >> 6);
    const int npair = N_UNLABEL / 2;

    float lacc = 0.0f;
    for (int pi = wave; pi < npair; pi += nwave) {
        const int i = pi * 2 + half;
        const int h = ut[i * 3 + 0], r = ut[i * 3 + 1], t = ut[i * 3 + 2];
        const float su  = triple_score_half(ent, rel, h, r, t, l);
        const float p   = sigmoidf_(su);
        const float tgt = fminf(fmaxf(p + pi_grad[i], 0.0f), 1.0f);
        const float loss = tgt * softplusf_(-su) + (1.0f - tgt) * softplusf_(su);
        if (l == 0) lacc += loss;   // one representative lane per half
    }
    lacc = wave_sum64(lacc);
    __shared__ float part[8];
    if (lane == 0) part[wid] = lacc;
    __syncthreads();
    if (threadIdx.x == 0) {
        float b = 0.0f;
        for (int w = 0; w < (int)(blockDim.x >> 6); ++w) b += part[w];
        atomicAdd(&accum[2], (double)b);
    }
}

// ---- Kernel C: positive + negative softplus sums AND sum-of-squares reg.
// Runs FIRST: the linear ent_emb sweep warms L3 for the gather kernels. ----
__global__ void aux_kernel(const float* __restrict__ pos,
                           const float* __restrict__ neg,
                           const float* __restrict__ ent,
                           const float* __restrict__ rel,
                           double* __restrict__ accum) {
    const int tid = blockIdx.x * blockDim.x + threadIdx.x;
    const int stride = gridDim.x * blockDim.x;
    float ps = 0.0f, ns = 0.0f, sq = 0.0f;
    for (int i = tid; i < POS_LEN / 4; i += stride) {
        float4 v = reinterpret_cast<const float4*>(pos)[i];
        ps += softplusf_(-v.x) + softplusf_(-v.y) + softplusf_(-v.z) + softplusf_(-v.w);
    }
    for (int i = tid; i < (POS_LEN * NUM_NEG) / 4; i += stride) {
        float4 v = reinterpret_cast<const float4*>(neg)[i];
        ns += softplusf_(v.x) + softplusf_(v.y) + softplusf_(v.z) + softplusf_(v.w);
    }
    for (int i = tid; i < (NUM_ENT * EMB_DIM) / 4; i += stride) {
        float4 v = reinterpret_cast<const float4*>(ent)[i];
        sq += v.x * v.x + v.y * v.y + v.z * v.z + v.w * v.w;
    }
    for (int i = tid; i < (NUM_REL * EMB_DIM) / 4; i += stride) {
        float4 v = reinterpret_cast<const float4*>(rel)[i];
        sq += v.x * v.x + v.y * v.y + v.z * v.z + v.w * v.w;
    }
    ps = wave_sum64(ps); ns = wave_sum64(ns); sq = wave_sum64(sq);
    __shared__ float lp[8], ln[8], ls[8];
    const int lane = threadIdx.x & 63, wid = threadIdx.x >> 6;
    if (lane == 0) { lp[wid] = ps; ln[wid] = ns; ls[wid] = sq; }
    __syncthreads();
    if (threadIdx.x == 0) {
        float bp = 0.0f, bn = 0.0f, bs = 0.0f;
        for (int w = 0; w < (int)(blockDim.x >> 6); ++w) { bp += lp[w]; bn += ln[w]; bs += ls[w]; }
        atomicAdd(&accum[0], (double)bp);
        atomicAdd(&accum[1], (double)bn);
        atomicAdd(&accum[3], (double)bs);
    }
}

// ---- Finalize ----
__global__ void finalize_kernel(const double* __restrict__ accum,
                                float* __restrict__ out) {
    double v = accum[0] / (double)POS_LEN
             + accum[1] / ((double)POS_LEN * (double)NUM_NEG)
             + accum[2] / (double)N_UNLABEL
             + WEIGHT_DECAY * accum[3];
    out[0] = (float)v;
}

extern "C" void kernel_launch(void* const* d_in, const int* in_sizes, int n_in,
                              void* d_out, int out_size, void* d_ws, size_t ws_size,
                              hipStream_t stream) {
    const float* pos  = (const float*)d_in[0];
    const float* neg  = (const float*)d_in[1];
    const float* conf = (const float*)d_in[2];
    const float* ent  = (const float*)d_in[3];
    const float* rel  = (const float*)d_in[4];
    const int*   p1   = (const int*)d_in[5];
    const int*   p2   = (const int*)d_in[6];
    const int*   tnum = (const int*)d_in[7];
    const int*   uids = (const int*)d_in[8];
    const int*   ut   = (const int*)d_in[9];

    float*  pi_grad = (float*)d_ws;
    double* accum   = (double*)((char*)d_ws + (size_t)N_UNLABEL * sizeof(float));

    hipMemsetAsync(d_ws, 0, (size_t)N_UNLABEL * sizeof(float) + 4 * sizeof(double), stream);

    // aux first: linear ent_emb sweep warms L3 before the gather kernels.
    aux_kernel<<<2048, 256, 0, stream>>>(pos, neg, ent, rel, accum);
    rules_kernel<<<2048, 256, 0, stream>>>(conf, ent, rel, p1, p2, tnum, uids, pi_grad);
    unlabel_kernel<<<1024, 256, 0, stream>>>(ent, rel, ut, pi_grad, accum);
    finalize_kernel<<<1, 1, 0, stream>>>(accum, (float*)d_out);
}

// Round 3
// 195.197 us; speedup vs baseline: 3.1501x; 1.3358x over previous
//
#include <hip/hip_runtime.h>
#include <cstddef>
#include <cstdint>

#define POS_LEN    32768
#define NUM_NEG    64
#define N_RULES    262144
#define N_UNLABEL  131072
#define NUM_ENT    100000
#define NUM_REL    500
#define EMB_DIM    256
#define WEIGHT_DECAY 1e-5

typedef __attribute__((ext_vector_type(8))) unsigned short u16x8;

__device__ __forceinline__ float softplusf_(float x) {
    return fmaxf(x, 0.0f) + log1pf(expf(-fabsf(x)));
}
__device__ __forceinline__ float sigmoidf_(float x) {
    return 1.0f / (1.0f + expf(-x));
}
__device__ __forceinline__ float half_sum32(float v) {
#pragma unroll
    for (int m = 1; m <= 16; m <<= 1) v += __shfl_xor(v, m, 64);
    return v;
}
__device__ __forceinline__ float wave_sum64(float v) {
#pragma unroll
    for (int m = 32; m >= 1; m >>= 1) v += __shfl_xor(v, m, 64);
    return v;
}
__device__ __forceinline__ unsigned short f2bf(float f) {
    unsigned u = __float_as_uint(f);
    return (unsigned short)((u + 0x7FFFu + ((u >> 16) & 1u)) >> 16);  // RNE
}
__device__ __forceinline__ float bf2f(unsigned short b) {
    return __uint_as_float((unsigned)b << 16);
}

// ---- bf16 half-wave triple score: 32 lanes x 8 elems = 256 dims ----
__device__ __forceinline__ float triple_score_bf16(const unsigned short* __restrict__ ent16,
                                                   const unsigned short* __restrict__ rel16,
                                                   int h, int r, int t, int l) {
    const u16x8 hv = *reinterpret_cast<const u16x8*>(ent16 + (size_t)h * EMB_DIM + l * 8);
    const u16x8 rv = *reinterpret_cast<const u16x8*>(rel16 + (size_t)r * EMB_DIM + l * 8);
    const u16x8 tv = *reinterpret_cast<const u16x8*>(ent16 + (size_t)t * EMB_DIM + l * 8);
    float s = 0.0f;
#pragma unroll
    for (int j = 0; j < 8; ++j)
        s = fmaf(bf2f(hv[j]) * bf2f(rv[j]), bf2f(tv[j]), s);
    return half_sum32(s);
}

// f32 half-wave score (fallback path)
__device__ __forceinline__ float triple_score_half(const float* __restrict__ ent,
                                                   const float* __restrict__ rel,
                                                   int h, int r, int t, int l) {
    const float4* hp = reinterpret_cast<const float4*>(ent + (size_t)h * EMB_DIM) + l * 2;
    const float4* rp = reinterpret_cast<const float4*>(rel + (size_t)r * EMB_DIM) + l * 2;
    const float4* tp = reinterpret_cast<const float4*>(ent + (size_t)t * EMB_DIM) + l * 2;
    float4 h0 = hp[0], h1 = hp[1];
    float4 r0 = rp[0], r1 = rp[1];
    float4 t0 = tp[0], t1 = tp[1];
    float s = h0.x * r0.x * t0.x + h0.y * r0.y * t0.y + h0.z * r0.z * t0.z + h0.w * r0.w * t0.w
            + h1.x * r1.x * t1.x + h1.y * r1.y * t1.y + h1.z * r1.z * t1.z + h1.w * r1.w * t1.w;
    return half_sum32(s);
}

// ---- Kernel 1: pos/neg softplus sums + sum-of-squares (f32, exact) + bf16 conversion ----
__global__ void aux_convert_kernel(const float* __restrict__ pos,
                                   const float* __restrict__ neg,
                                   const float* __restrict__ ent,
                                   const float* __restrict__ rel,
                                   unsigned short* __restrict__ ent16,
                                   unsigned short* __restrict__ rel16,
                                   double* __restrict__ accum) {
    const int tid = blockIdx.x * blockDim.x + threadIdx.x;
    const int stride = gridDim.x * blockDim.x;
    float ps = 0.0f, ns = 0.0f, sq = 0.0f;
    for (int i = tid; i < POS_LEN / 4; i += stride) {
        float4 v = reinterpret_cast<const float4*>(pos)[i];
        ps += softplusf_(-v.x) + softplusf_(-v.y) + softplusf_(-v.z) + softplusf_(-v.w);
    }
    for (int i = tid; i < (POS_LEN * NUM_NEG) / 4; i += stride) {
        float4 v = reinterpret_cast<const float4*>(neg)[i];
        ns += softplusf_(v.x) + softplusf_(v.y) + softplusf_(v.z) + softplusf_(v.w);
    }
    // ent: read 8 f32, accumulate squares (f32 source), write 8 bf16 (16 B)
    for (int i = tid; i < (NUM_ENT * EMB_DIM) / 8; i += stride) {
        const float4* src = reinterpret_cast<const float4*>(ent) + (size_t)i * 2;
        float4 a = src[0], b = src[1];
        sq += a.x * a.x + a.y * a.y + a.z * a.z + a.w * a.w
            + b.x * b.x + b.y * b.y + b.z * b.z + b.w * b.w;
        u16x8 o;
        o[0] = f2bf(a.x); o[1] = f2bf(a.y); o[2] = f2bf(a.z); o[3] = f2bf(a.w);
        o[4] = f2bf(b.x); o[5] = f2bf(b.y); o[6] = f2bf(b.z); o[7] = f2bf(b.w);
        *reinterpret_cast<u16x8*>(ent16 + (size_t)i * 8) = o;
    }
    for (int i = tid; i < (NUM_REL * EMB_DIM) / 8; i += stride) {
        const float4* src = reinterpret_cast<const float4*>(rel) + (size_t)i * 2;
        float4 a = src[0], b = src[1];
        sq += a.x * a.x + a.y * a.y + a.z * a.z + a.w * a.w
            + b.x * b.x + b.y * b.y + b.z * b.z + b.w * b.w;
        u16x8 o;
        o[0] = f2bf(a.x); o[1] = f2bf(a.y); o[2] = f2bf(a.z); o[3] = f2bf(a.w);
        o[4] = f2bf(b.x); o[5] = f2bf(b.y); o[6] = f2bf(b.z); o[7] = f2bf(b.w);
        *reinterpret_cast<u16x8*>(rel16 + (size_t)i * 8) = o;
    }
    ps = wave_sum64(ps); ns = wave_sum64(ns); sq = wave_sum64(sq);
    __shared__ float lp[8], ln[8], ls[8];
    const int lane = threadIdx.x & 63, wid = threadIdx.x >> 6;
    if (lane == 0) { lp[wid] = ps; ln[wid] = ns; ls[wid] = sq; }
    __syncthreads();
    if (threadIdx.x == 0) {
        float bp = 0.0f, bn = 0.0f, bs = 0.0f;
        for (int w = 0; w < (int)(blockDim.x >> 6); ++w) { bp += lp[w]; bn += ln[w]; bs += ls[w]; }
        atomicAdd(&accum[0], (double)bp);
        atomicAdd(&accum[1], (double)bn);
        atomicAdd(&accum[3], (double)bs);
    }
}

// ---- Kernel 2: fused gathers. Rules -> atomic pi_grad; unlabel -> su store. ----
__global__ void gather_kernel(const float* __restrict__ conf,
                              const unsigned short* __restrict__ ent16,
                              const unsigned short* __restrict__ rel16,
                              const int* __restrict__ p1,
                              const int* __restrict__ p2,
                              const int* __restrict__ tnum,
                              const int* __restrict__ uids,
                              const int* __restrict__ ut,
                              float* __restrict__ pi_grad,
                              float* __restrict__ su_out) {
    const int lane = threadIdx.x & 63;
    const int l    = lane & 31;
    const int half = lane >> 5;
    const int wave  = blockIdx.x * (blockDim.x >> 6) + (threadIdx.x >> 6);
    const int nwave = gridDim.x * (blockDim.x >> 6);
    const int nrp = N_RULES / 2, nup = N_UNLABEL / 2, ntot = nrp + nup;

    for (int pi = wave; pi < ntot; pi += nwave) {
        if (pi < nrp) {
            const int rule = pi * 2 + half;
            const int h1 = p1[rule * 3 + 0], r1 = p1[rule * 3 + 1], t1 = p1[rule * 3 + 2];
            float c = sigmoidf_(triple_score_bf16(ent16, rel16, h1, r1, t1, l)) * conf[rule];
            if (tnum[rule] == 3) {
                const int h2 = p2[rule * 3 + 0], r2 = p2[rule * 3 + 1], t2 = p2[rule * 3 + 2];
                c *= sigmoidf_(triple_score_bf16(ent16, rel16, h2, r2, t2, l));
            }
            if (l == 0) atomicAdd(&pi_grad[uids[rule]], c);
        } else {
            const int i = (pi - nrp) * 2 + half;
            const int h = ut[i * 3 + 0], r = ut[i * 3 + 1], t = ut[i * 3 + 2];
            const float su = triple_score_bf16(ent16, rel16, h, r, t, l);
            if (l == 0) su_out[i] = su;
        }
    }
}

// ---- Kernel 3: unlabel loss from stored su + pi_grad ----
__global__ void loss_kernel(const float* __restrict__ su,
                            const float* __restrict__ pi_grad,
                            double* __restrict__ accum) {
    const int tid = blockIdx.x * blockDim.x + threadIdx.x;
    const int stride = gridDim.x * blockDim.x;
    float acc = 0.0f;
    for (int i = tid; i < N_UNLABEL; i += stride) {
        const float s   = su[i];
        const float p   = sigmoidf_(s);
        const float tgt = fminf(fmaxf(p + pi_grad[i], 0.0f), 1.0f);
        acc += tgt * softplusf_(-s) + (1.0f - tgt) * softplusf_(s);
    }
    acc = wave_sum64(acc);
    __shared__ float part[8];
    const int lane = threadIdx.x & 63, wid = threadIdx.x >> 6;
    if (lane == 0) part[wid] = acc;
    __syncthreads();
    if (threadIdx.x == 0) {
        float b = 0.0f;
        for (int w = 0; w < (int)(blockDim.x >> 6); ++w) b += part[w];
        atomicAdd(&accum[2], (double)b);
    }
}

// ---- Fallback f32 kernels (used only if ws_size too small for bf16 copies) ----
__global__ void rules_kernel_f32(const float* __restrict__ conf,
                                 const float* __restrict__ ent,
                                 const float* __restrict__ rel,
                                 const int* __restrict__ p1,
                                 const int* __restrict__ p2,
                                 const int* __restrict__ tnum,
                                 const int* __restrict__ uids,
                                 float* __restrict__ pi_grad) {
    const int lane = threadIdx.x & 63;
    const int l    = lane & 31;
    const int half = lane >> 5;
    const int wave  = blockIdx.x * (blockDim.x >> 6) + (threadIdx.x >> 6);
    const int nwave = gridDim.x * (blockDim.x >> 6);
    for (int pi = wave; pi < N_RULES / 2; pi += nwave) {
        const int rule = pi * 2 + half;
        const int h1 = p1[rule * 3 + 0], r1 = p1[rule * 3 + 1], t1 = p1[rule * 3 + 2];
        float c = sigmoidf_(triple_score_half(ent, rel, h1, r1, t1, l)) * conf[rule];
        if (tnum[rule] == 3) {
            const int h2 = p2[rule * 3 + 0], r2 = p2[rule * 3 + 1], t2 = p2[rule * 3 + 2];
            c *= sigmoidf_(triple_score_half(ent, rel, h2, r2, t2, l));
        }
        if (l == 0) atomicAdd(&pi_grad[uids[rule]], c);
    }
}
__global__ void unlabel_kernel_f32(const float* __restrict__ ent,
                                   const float* __restrict__ rel,
                                   const int* __restrict__ ut,
                                   const float* __restrict__ pi_grad,
                                   double* __restrict__ accum) {
    const int lane = threadIdx.x & 63;
    const int l    = lane & 31;
    const int half = lane >> 5;
    const int wid  = threadIdx.x >> 6;
    const int wave  = blockIdx.x * (blockDim.x >> 6) + wid;
    const int nwave = gridDim.x * (blockDim.x >> 6);
    float lacc = 0.0f;
    for (int pi = wave; pi < N_UNLABEL / 2; pi += nwave) {
        const int i = pi * 2 + half;
        const int h = ut[i * 3 + 0], r = ut[i * 3 + 1], t = ut[i * 3 + 2];
        const float su  = triple_score_half(ent, rel, h, r, t, l);
        const float p   = sigmoidf_(su);
        const float tgt = fminf(fmaxf(p + pi_grad[i], 0.0f), 1.0f);
        const float loss = tgt * softplusf_(-su) + (1.0f - tgt) * softplusf_(su);
        if (l == 0) lacc += loss;
    }
    lacc = wave_sum64(lacc);
    __shared__ float part[8];
    if (lane == 0) part[wid] = lacc;
    __syncthreads();
    if (threadIdx.x == 0) {
        float b = 0.0f;
        for (int w = 0; w < (int)(blockDim.x >> 6); ++w) b += part[w];
        atomicAdd(&accum[2], (double)b);
    }
}
__global__ void aux_kernel_f32(const float* __restrict__ pos,
                               const float* __restrict__ neg,
                               const float* __restrict__ ent,
                               const float* __restrict__ rel,
                               double* __restrict__ accum) {
    const int tid = blockIdx.x * blockDim.x + threadIdx.x;
    const int stride = gridDim.x * blockDim.x;
    float ps = 0.0f, ns = 0.0f, sq = 0.0f;
    for (int i = tid; i < POS_LEN / 4; i += stride) {
        float4 v = reinterpret_cast<const float4*>(pos)[i];
        ps += softplusf_(-v.x) + softplusf_(-v.y) + softplusf_(-v.z) + softplusf_(-v.w);
    }
    for (int i = tid; i < (POS_LEN * NUM_NEG) / 4; i += stride) {
        float4 v = reinterpret_cast<const float4*>(neg)[i];
        ns += softplusf_(v.x) + softplusf_(v.y) + softplusf_(v.z) + softplusf_(v.w);
    }
    for (int i = tid; i < (NUM_ENT * EMB_DIM) / 4; i += stride) {
        float4 v = reinterpret_cast<const float4*>(ent)[i];
        sq += v.x * v.x + v.y * v.y + v.z * v.z + v.w * v.w;
    }
    for (int i = tid; i < (NUM_REL * EMB_DIM) / 4; i += stride) {
        float4 v = reinterpret_cast<const float4*>(rel)[i];
        sq += v.x * v.x + v.y * v.y + v.z * v.z + v.w * v.w;
    }
    ps = wave_sum64(ps); ns = wave_sum64(ns); sq = wave_sum64(sq);
    __shared__ float lp[8], ln[8], ls[8];
    const int lane = threadIdx.x & 63, wid = threadIdx.x >> 6;
    if (lane == 0) { lp[wid] = ps; ln[wid] = ns; ls[wid] = sq; }
    __syncthreads();
    if (threadIdx.x == 0) {
        float bp = 0.0f, bn = 0.0f, bs = 0.0f;
        for (int w = 0; w < (int)(blockDim.x >> 6); ++w) { bp += lp[w]; bn += ln[w]; bs += ls[w]; }
        atomicAdd(&accum[0], (double)bp);
        atomicAdd(&accum[1], (double)bn);
        atomicAdd(&accum[3], (double)bs);
    }
}

// ---- Finalize ----
__global__ void finalize_kernel(const double* __restrict__ accum,
                                float* __restrict__ out) {
    double v = accum[0] / (double)POS_LEN
             + accum[1] / ((double)POS_LEN * (double)NUM_NEG)
             + accum[2] / (double)N_UNLABEL
             + WEIGHT_DECAY * accum[3];
    out[0] = (float)v;
}

extern "C" void kernel_launch(void* const* d_in, const int* in_sizes, int n_in,
                              void* d_out, int out_size, void* d_ws, size_t ws_size,
                              hipStream_t stream) {
    const float* pos  = (const float*)d_in[0];
    const float* neg  = (const float*)d_in[1];
    const float* conf = (const float*)d_in[2];
    const float* ent  = (const float*)d_in[3];
    const float* rel  = (const float*)d_in[4];
    const int*   p1   = (const int*)d_in[5];
    const int*   p2   = (const int*)d_in[6];
    const int*   tnum = (const int*)d_in[7];
    const int*   uids = (const int*)d_in[8];
    const int*   ut   = (const int*)d_in[9];

    // ws layout
    const size_t off_pi    = 0;                                   // 512 KB f32
    const size_t off_accum = (size_t)N_UNLABEL * 4;               // 64 B (4 f64)
    const size_t off_su    = off_accum + 64;                      // 512 KB f32
    const size_t off_ent16 = off_su + (size_t)N_UNLABEL * 4;      // 51.2 MB bf16
    const size_t off_rel16 = off_ent16 + (size_t)NUM_ENT * EMB_DIM * 2;
    const size_t needed    = off_rel16 + (size_t)NUM_REL * EMB_DIM * 2;

    float*  pi_grad = (float*)((char*)d_ws + off_pi);
    double* accum   = (double*)((char*)d_ws + off_accum);

    // zero pi_grad + accum every call (ws poisoned once, never re-poisoned)
    hipMemsetAsync(d_ws, 0, off_su, stream);

    if (ws_size >= needed) {
        float*          su    = (float*)((char*)d_ws + off_su);
        unsigned short* ent16 = (unsigned short*)((char*)d_ws + off_ent16);
        unsigned short* rel16 = (unsigned short*)((char*)d_ws + off_rel16);

        aux_convert_kernel<<<2048, 256, 0, stream>>>(pos, neg, ent, rel, ent16, rel16, accum);
        gather_kernel<<<2048, 256, 0, stream>>>(conf, ent16, rel16, p1, p2, tnum, uids, ut,
                                                pi_grad, su);
        loss_kernel<<<128, 256, 0, stream>>>(su, pi_grad, accum);
    } else {
        aux_kernel_f32<<<2048, 256, 0, stream>>>(pos, neg, ent, rel, accum);
        rules_kernel_f32<<<2048, 256, 0, stream>>>(conf, ent, rel, p1, p2, tnum, uids, pi_grad);
        unlabel_kernel_f32<<<1024, 256, 0, stream>>>(ent, rel, ut, pi_grad, accum);
    }
    finalize_kernel<<<1, 1, 0, stream>>>(accum, (float*)d_out);
}

// Round 4
// 108.784 us; speedup vs baseline: 5.6523x; 1.7944x over previous
//
#include <hip/hip_runtime.h>
#include <cstddef>
#include <cstdint>

#define POS_LEN    32768
#define NUM_NEG    64
#define N_RULES    262144
#define N_UNLABEL  131072
#define NUM_ENT    100000
#define NUM_REL    500
#define EMB_DIM    256
#define WEIGHT_DECAY 1e-5

#define AUX_BLOCKS    2048
#define GATHER_BLOCKS 2048
#define LOSS_BLOCKS   256

typedef __attribute__((ext_vector_type(4))) float        f32x4;
typedef __attribute__((ext_vector_type(2))) unsigned int u32x2;

__device__ __forceinline__ float softplusf_(float x) {
    return fmaxf(x, 0.0f) + log1pf(expf(-fabsf(x)));
}
__device__ __forceinline__ float sigmoidf_(float x) {
    return 1.0f / (1.0f + expf(-x));
}
__device__ __forceinline__ float half_sum32(float v) {
#pragma unroll
    for (int m = 1; m <= 16; m <<= 1) v += __shfl_xor(v, m, 64);
    return v;
}
__device__ __forceinline__ float wave_sum64(float v) {
#pragma unroll
    for (int m = 32; m >= 1; m >>= 1) v += __shfl_xor(v, m, 64);
    return v;
}
__device__ __forceinline__ double wave_sum64d(double v) {
#pragma unroll
    for (int m = 32; m >= 1; m >>= 1) v += __shfl_xor(v, m, 64);
    return v;
}

// ---- fp8 (OCP e4m3) pack/unpack via gfx950 HW converts ----
__device__ __forceinline__ u32x2 f32x8_to_fp8(const f32x4 a, const f32x4 b) {
    int lo = 0, hi = 0;
    lo = __builtin_amdgcn_cvt_pk_fp8_f32(a[0], a[1], lo, false);
    lo = __builtin_amdgcn_cvt_pk_fp8_f32(a[2], a[3], lo, true);
    hi = __builtin_amdgcn_cvt_pk_fp8_f32(b[0], b[1], hi, false);
    hi = __builtin_amdgcn_cvt_pk_fp8_f32(b[2], b[3], hi, true);
    u32x2 r; r[0] = (unsigned)lo; r[1] = (unsigned)hi; return r;
}
__device__ __forceinline__ void fp8x4_to_f32(unsigned int w, float* o) {
    auto x = __builtin_amdgcn_cvt_pk_f32_fp8((int)w, false);
    auto y = __builtin_amdgcn_cvt_pk_f32_fp8((int)w, true);
    o[0] = x[0]; o[1] = x[1]; o[2] = y[0]; o[3] = y[1];
}

// Half-wave fp8 triple score: 32 lanes x 8 fp8 (8 B) = 256 dims. l = lane & 31.
__device__ __forceinline__ float triple_score_fp8(const u32x2* __restrict__ ent8,
                                                  const u32x2* __restrict__ rel8,
                                                  int h, int r, int t, int l) {
    const u32x2 hv = ent8[(size_t)h * 32 + l];
    const u32x2 rv = rel8[(size_t)r * 32 + l];
    const u32x2 tv = ent8[(size_t)t * 32 + l];
    float hf[8], rf[8], tf[8];
    fp8x4_to_f32(hv[0], hf); fp8x4_to_f32(hv[1], hf + 4);
    fp8x4_to_f32(rv[0], rf); fp8x4_to_f32(rv[1], rf + 4);
    fp8x4_to_f32(tv[0], tf); fp8x4_to_f32(tv[1], tf + 4);
    float s = 0.0f;
#pragma unroll
    for (int j = 0; j < 8; ++j) s = fmaf(hf[j] * rf[j], tf[j], s);
    return half_sum32(s);
}

// ---- Kernel 1: pos/neg softplus + sum-of-squares (f32 exact) + fp8 quantize
//      + zero pi_grad. Streaming f32 reads are NON-TEMPORAL so the fp8 table
//      stays L3-resident for the gather kernel. Per-block partials, NO atomics. ----
__global__ void aux_convert_kernel(const float* __restrict__ pos,
                                   const float* __restrict__ neg,
                                   const float* __restrict__ ent,
                                   const float* __restrict__ rel,
                                   u32x2* __restrict__ ent8,
                                   u32x2* __restrict__ rel8,
                                   float* __restrict__ pi_grad,
                                   float* __restrict__ auxp) {
    const int tid = blockIdx.x * blockDim.x + threadIdx.x;
    const int stride = gridDim.x * blockDim.x;

    for (int i = tid; i < N_UNLABEL; i += stride) pi_grad[i] = 0.0f;

    float ps = 0.0f, ns = 0.0f, sq = 0.0f;
    const f32x4* posv = reinterpret_cast<const f32x4*>(pos);
    const f32x4* negv = reinterpret_cast<const f32x4*>(neg);
    for (int i = tid; i < POS_LEN / 4; i += stride) {
        f32x4 v = __builtin_nontemporal_load(posv + i);
        ps += softplusf_(-v[0]) + softplusf_(-v[1]) + softplusf_(-v[2]) + softplusf_(-v[3]);
    }
    for (int i = tid; i < (POS_LEN * NUM_NEG) / 4; i += stride) {
        f32x4 v = __builtin_nontemporal_load(negv + i);
        ns += softplusf_(v[0]) + softplusf_(v[1]) + softplusf_(v[2]) + softplusf_(v[3]);
    }
    const f32x4* entv = reinterpret_cast<const f32x4*>(ent);
    for (int i = tid; i < (NUM_ENT * EMB_DIM) / 8; i += stride) {
        f32x4 a = __builtin_nontemporal_load(entv + (size_t)i * 2);
        f32x4 b = __builtin_nontemporal_load(entv + (size_t)i * 2 + 1);
        sq += a[0]*a[0] + a[1]*a[1] + a[2]*a[2] + a[3]*a[3]
            + b[0]*b[0] + b[1]*b[1] + b[2]*b[2] + b[3]*b[3];
        ent8[i] = f32x8_to_fp8(a, b);
    }
    const f32x4* relv = reinterpret_cast<const f32x4*>(rel);
    for (int i = tid; i < (NUM_REL * EMB_DIM) / 8; i += stride) {
        f32x4 a = __builtin_nontemporal_load(relv + (size_t)i * 2);
        f32x4 b = __builtin_nontemporal_load(relv + (size_t)i * 2 + 1);
        sq += a[0]*a[0] + a[1]*a[1] + a[2]*a[2] + a[3]*a[3]
            + b[0]*b[0] + b[1]*b[1] + b[2]*b[2] + b[3]*b[3];
        rel8[i] = f32x8_to_fp8(a, b);
    }

    ps = wave_sum64(ps); ns = wave_sum64(ns); sq = wave_sum64(sq);
    __shared__ float lp[8], ln[8], ls[8];
    const int lane = threadIdx.x & 63, wid = threadIdx.x >> 6;
    if (lane == 0) { lp[wid] = ps; ln[wid] = ns; ls[wid] = sq; }
    __syncthreads();
    if (threadIdx.x == 0) {
        float bp = 0.0f, bn = 0.0f, bs = 0.0f;
        for (int w = 0; w < (int)(blockDim.x >> 6); ++w) { bp += lp[w]; bn += ln[w]; bs += ls[w]; }
        auxp[blockIdx.x]                  = bp;   // no atomics: per-block slots
        auxp[AUX_BLOCKS + blockIdx.x]     = bn;
        auxp[2 * AUX_BLOCKS + blockIdx.x] = bs;
    }
}

// ---- Kernel 2: fused fp8 gathers. Rules -> atomic into pi_grad (scattered);
//      unlabel -> su store. 2 triples per wave (one per 32-lane half). ----
__global__ void gather_kernel(const float* __restrict__ conf,
                              const u32x2* __restrict__ ent8,
                              const u32x2* __restrict__ rel8,
                              const int* __restrict__ p1,
                              const int* __restrict__ p2,
                              const int* __restrict__ tnum,
                              const int* __restrict__ uids,
                              const int* __restrict__ ut,
                              float* __restrict__ pi_grad,
                              float* __restrict__ su_out) {
    const int lane = threadIdx.x & 63;
    const int l    = lane & 31;
    const int half = lane >> 5;
    const int wave  = blockIdx.x * (blockDim.x >> 6) + (threadIdx.x >> 6);
    const int nwave = gridDim.x * (blockDim.x >> 6);
    const int nrp = N_RULES / 2, nup = N_UNLABEL / 2, ntot = nrp + nup;

    for (int pi = wave; pi < ntot; pi += nwave) {
        if (pi < nrp) {
            const int rule = pi * 2 + half;
            const int h1 = p1[rule * 3 + 0], r1 = p1[rule * 3 + 1], t1 = p1[rule * 3 + 2];
            float c = sigmoidf_(triple_score_fp8(ent8, rel8, h1, r1, t1, l)) * conf[rule];
            if (tnum[rule] == 3) {
                const int h2 = p2[rule * 3 + 0], r2 = p2[rule * 3 + 1], t2 = p2[rule * 3 + 2];
                c *= sigmoidf_(triple_score_fp8(ent8, rel8, h2, r2, t2, l));
            }
            if (l == 0) atomicAdd(&pi_grad[uids[rule]], c);
        } else {
            const int i = (pi - nrp) * 2 + half;
            const int h = ut[i * 3 + 0], r = ut[i * 3 + 1], t = ut[i * 3 + 2];
            const float su = triple_score_fp8(ent8, rel8, h, r, t, l);
            if (l == 0) su_out[i] = su;
        }
    }
}

// ---- Kernel 3: unlabel loss from stored su + pi_grad. Per-block partials. ----
__global__ void loss_kernel(const float* __restrict__ su,
                            const float* __restrict__ pi_grad,
                            float* __restrict__ lossp) {
    const int tid = blockIdx.x * blockDim.x + threadIdx.x;
    const int stride = gridDim.x * blockDim.x;
    float acc = 0.0f;
    for (int i = tid; i < N_UNLABEL; i += stride) {
        const float s   = su[i];
        const float p   = sigmoidf_(s);
        const float tgt = fminf(fmaxf(p + pi_grad[i], 0.0f), 1.0f);
        acc += tgt * softplusf_(-s) + (1.0f - tgt) * softplusf_(s);
    }
    acc = wave_sum64(acc);
    __shared__ float part[8];
    const int lane = threadIdx.x & 63, wid = threadIdx.x >> 6;
    if (lane == 0) part[wid] = acc;
    __syncthreads();
    if (threadIdx.x == 0) {
        float b = 0.0f;
        for (int w = 0; w < (int)(blockDim.x >> 6); ++w) b += part[w];
        lossp[blockIdx.x] = b;
    }
}

// ---- Kernel 4: single-wave finalize — sum all partials in f64, emit loss. ----
__global__ void finalize_kernel(const float* __restrict__ auxp,
                                const float* __restrict__ lossp,
                                float* __restrict__ out) {
    const int lane = threadIdx.x;  // 64 threads
    double ps = 0.0, ns = 0.0, sq = 0.0, ul = 0.0;
    for (int i = lane; i < AUX_BLOCKS; i += 64) {
        ps += (double)auxp[i];
        ns += (double)auxp[AUX_BLOCKS + i];
        sq += (double)auxp[2 * AUX_BLOCKS + i];
    }
    for (int i = lane; i < LOSS_BLOCKS; i += 64) ul += (double)lossp[i];
    ps = wave_sum64d(ps); ns = wave_sum64d(ns);
    sq = wave_sum64d(sq); ul = wave_sum64d(ul);
    if (lane == 0) {
        double v = ps / (double)POS_LEN
                 + ns / ((double)POS_LEN * (double)NUM_NEG)
                 + ul / (double)N_UNLABEL
                 + WEIGHT_DECAY * sq;
        out[0] = (float)v;
    }
}

extern "C" void kernel_launch(void* const* d_in, const int* in_sizes, int n_in,
                              void* d_out, int out_size, void* d_ws, size_t ws_size,
                              hipStream_t stream) {
    const float* pos  = (const float*)d_in[0];
    const float* neg  = (const float*)d_in[1];
    const float* conf = (const float*)d_in[2];
    const float* ent  = (const float*)d_in[3];
    const float* rel  = (const float*)d_in[4];
    const int*   p1   = (const int*)d_in[5];
    const int*   p2   = (const int*)d_in[6];
    const int*   tnum = (const int*)d_in[7];
    const int*   uids = (const int*)d_in[8];
    const int*   ut   = (const int*)d_in[9];

    // ws layout (bytes); all regions written unconditionally every call.
    const size_t off_pi    = 0;                                     // 512 KB
    const size_t off_su    = off_pi + (size_t)N_UNLABEL * 4;        // 512 KB
    const size_t off_auxp  = off_su + (size_t)N_UNLABEL * 4;        // 24 KB
    const size_t off_lossp = off_auxp + (size_t)3 * AUX_BLOCKS * 4; // 1 KB
    const size_t off_ent8  = (off_lossp + (size_t)LOSS_BLOCKS * 4 + 511) & ~(size_t)511;
    const size_t off_rel8  = off_ent8 + (size_t)NUM_ENT * EMB_DIM;  // fp8: 1 B/elem

    float* pi_grad = (float*)((char*)d_ws + off_pi);
    float* su      = (float*)((char*)d_ws + off_su);
    float* auxp    = (float*)((char*)d_ws + off_auxp);
    float* lossp   = (float*)((char*)d_ws + off_lossp);
    u32x2* ent8    = (u32x2*)((char*)d_ws + off_ent8);
    u32x2* rel8    = (u32x2*)((char*)d_ws + off_rel8);

    aux_convert_kernel<<<AUX_BLOCKS, 256, 0, stream>>>(pos, neg, ent, rel,
                                                       ent8, rel8, pi_grad, auxp);
    gather_kernel<<<GATHER_BLOCKS, 256, 0, stream>>>(conf, ent8, rel8, p1, p2, tnum,
                                                     uids, ut, pi_grad, su);
    loss_kernel<<<LOSS_BLOCKS, 256, 0, stream>>>(su, pi_grad, lossp);
    finalize_kernel<<<1, 64, 0, stream>>>(auxp, lossp, (float*)d_out);
}